// Round 11
// baseline (1213.326 us; speedup 1.0000x reference)
//
#include <hip/hip_runtime.h>
#include <math.h>

// Problem constants (reference: B,T,D=16,512,256; HS=512, D_A=64, R=8)
#define BB 16
#define TT 512
#define DD 256
#define HS 512
#define DA 64
#define RR 8
#define G4H 2048   // 4*HS

typedef __attribute__((ext_vector_type(2))) float f2;
typedef __attribute__((ext_vector_type(8))) short bf16x8;
typedef __attribute__((ext_vector_type(4))) float f32x4;
typedef unsigned short ushort_t;

// -------- workspace layout (float offsets) --------
// s     :        0  (B*T*R = 65536)   <- k5's hbuf64 overlays (dead by k4)
// e     :    65536
// inv   :   131072
// Mb    :   196608  (bf16, B*T*D ushorts)
// Wtb   :  1245184  (bf16, 2048x256 ushorts)
// gates :  2293760  (B*T*4H floats)

__device__ __forceinline__ ushort_t f2bf(float f) {
  const unsigned u = __float_as_uint(f);
  return (ushort_t)((u + 0x7FFFu + ((u >> 16) & 1u)) >> 16);  // RNE
}

// ============================================================
// K0w: Wtb[n][k] = bf16(W_ih[k][n])   (2048x256 <- 256x2048)
// ============================================================
__global__ __launch_bounds__(256) void k0w_transpose(
    const float* __restrict__ W, ushort_t* __restrict__ Wt) {
  __shared__ float tl[64][65];
  const int kb = (blockIdx.x & 3) * 64;
  const int nb = (blockIdx.x >> 2) * 64;
  const int tid = threadIdx.x;
  for (int i = tid; i < 4096; i += 256)
    tl[i >> 6][i & 63] = W[(kb + (i >> 6)) * 2048 + nb + (i & 63)];
  __syncthreads();
  for (int i = tid; i < 4096; i += 256) {
    const int n = i >> 6, k = i & 63;
    Wt[(nb + n) * 256 + kb + k] = f2bf(tl[k][n]);
  }
}

// ============================================================
// K1: s[b,t,r] = tanh(x[b,t,:] @ w1 + b1) @ w2 + b2
// ============================================================
__global__ __launch_bounds__(256) void k1_score(
    const float* __restrict__ x, const float* __restrict__ w1,
    const float* __restrict__ b1, const float* __restrict__ w2,
    const float* __restrict__ b2, float* __restrict__ s_out) {
  const int wave = threadIdx.x >> 6;
  const int lane = threadIdx.x & 63;
  for (int i = 0; i < 4; ++i) {
    const int bt = blockIdx.x * 16 + wave * 4 + i;
    const float* xr = x + bt * DD;
    float acc = b1[lane];
    #pragma unroll 4
    for (int d = 0; d < DD; ++d)
      acc = fmaf(xr[d], w1[d * DA + lane], acc);
    const float a = tanhf(acc);
    #pragma unroll
    for (int r = 0; r < RR; ++r) {
      float v = a * w2[lane * RR + r];
      for (int off = 32; off > 0; off >>= 1) v += __shfl_xor(v, off);
      if (lane == 0) s_out[bt * RR + r] = v + b2[r];
    }
  }
}

// ============================================================
// K2: per (b,r): m=max_t s; e=exp(s-m); den=inclusive prefix sum
// ============================================================
__global__ __launch_bounds__(512) void k2_prefix(
    const float* __restrict__ s_in, float* __restrict__ e_out,
    float* __restrict__ inv_out) {
  const int b = blockIdx.x >> 3, r = blockIdx.x & 7;
  const int t = threadIdx.x;
  __shared__ float red[TT];
  __shared__ float buf[2][TT];
  const float v = s_in[(b * TT + t) * RR + r];
  red[t] = v;
  __syncthreads();
  for (int off = 256; off >= 1; off >>= 1) {
    if (t < off) red[t] = fmaxf(red[t], red[t + off]);
    __syncthreads();
  }
  const float m = red[0];
  const float e = expf(v - m);
  int p = 0;
  buf[0][t] = e;
  __syncthreads();
  for (int off = 1; off < TT; off <<= 1) {
    const float add = (t >= off) ? buf[p][t - off] : 0.f;
    buf[1 - p][t] = buf[p][t] + add;
    __syncthreads();
    p ^= 1;
  }
  const float den = buf[p][t];
  e_out[(b * TT + t) * RR + r] = e;
  inv_out[(b * TT + t) * RR + r] = 1.0f / den;
}

// ============================================================
// K3: M scan -> bf16. v2: software-pipelined x prefetch (2 ahead).
// Old version was 1-wave-per-CU latency-bound on the serial 512-step
// scan (~85us); prefetch hides the ~900cyc HBM/LLC latency.
// ============================================================
__global__ __launch_bounds__(64) void k3_mix(
    const float* __restrict__ x, const float* __restrict__ e_in,
    const float* __restrict__ inv_in, ushort_t* __restrict__ Mout) {
  const int b = blockIdx.x >> 2;
  const int d = (blockIdx.x & 3) * 64 + threadIdx.x;
  __shared__ __align__(16) float el[TT * RR];
  __shared__ __align__(16) float il[TT * RR];
  for (int i = threadIdx.x * 4; i < TT * RR; i += 64 * 4) {
    *(float4*)&el[i] = *(const float4*)&e_in[b * TT * RR + i];
    *(float4*)&il[i] = *(const float4*)&inv_in[b * TT * RR + i];
  }
  __syncthreads();
  const float* xp = x + (long)b * TT * DD + d;
  float xv_c = xp[0];
  float xv_n = xp[DD];
  float4 c0 = {0.f, 0.f, 0.f, 0.f}, c1 = {0.f, 0.f, 0.f, 0.f};
  for (int t = 0; t < TT; ++t) {
    const float xv_f = (t + 2 < TT) ? xp[(t + 2) * DD] : 0.f;
    const float4 e0 = *(const float4*)&el[t * RR];
    const float4 e1 = *(const float4*)&el[t * RR + 4];
    const float4 i0 = *(const float4*)&il[t * RR];
    const float4 i1 = *(const float4*)&il[t * RR + 4];
    c0.x = fmaf(e0.x, xv_c, c0.x); c0.y = fmaf(e0.y, xv_c, c0.y);
    c0.z = fmaf(e0.z, xv_c, c0.z); c0.w = fmaf(e0.w, xv_c, c0.w);
    c1.x = fmaf(e1.x, xv_c, c1.x); c1.y = fmaf(e1.y, xv_c, c1.y);
    c1.z = fmaf(e1.z, xv_c, c1.z); c1.w = fmaf(e1.w, xv_c, c1.w);
    float msum = c0.x * i0.x + c0.y * i0.y + c0.z * i0.z + c0.w * i0.w;
    msum += c1.x * i1.x + c1.y * i1.y + c1.z * i1.z + c1.w * i1.w;
    Mout[(b * TT + t) * DD + d] = f2bf(msum * 0.125f);
    xv_c = xv_n;
    xv_n = xv_f;
  }
}

// ============================================================
// K4 (MFMA): gates = Mb(8192x256 bf16) @ Wtb^T + bias
// 128x128 tile, BK=32, 4 waves x (64x64), 16x16x32_bf16.
// ============================================================
__global__ __launch_bounds__(256) void k4_mfma(
    const ushort_t* __restrict__ Mb, const ushort_t* __restrict__ Wtb,
    const float* __restrict__ bias, float* __restrict__ C) {
  const int bn = blockIdx.x & 15;
  const int bm = blockIdx.x >> 4;
  const int tid = threadIdx.x;
  const int wv = tid >> 6, lane = tid & 63;
  const int quad = lane >> 4, l16 = lane & 15;
  const int wm = (wv & 1) * 64, wn = (wv >> 1) * 64;
  const int row0 = bm * 128, col0 = bn * 128;

  __shared__ __align__(16) ushort_t As[128][40];
  __shared__ __align__(16) ushort_t Bs[128][40];

  f32x4 acc[4][4];
  #pragma unroll
  for (int i = 0; i < 4; ++i)
    #pragma unroll
    for (int j = 0; j < 4; ++j) acc[i][j] = (f32x4){0.f, 0.f, 0.f, 0.f};

  const int r = tid >> 1, koff = (tid & 1) * 16;
  for (int k0 = 0; k0 < 256; k0 += 32) {
    const uint4 av0 = *(const uint4*)&Mb[(row0 + r) * 256 + k0 + koff];
    const uint4 av1 = *(const uint4*)&Mb[(row0 + r) * 256 + k0 + koff + 8];
    const uint4 bv0 = *(const uint4*)&Wtb[(col0 + r) * 256 + k0 + koff];
    const uint4 bv1 = *(const uint4*)&Wtb[(col0 + r) * 256 + k0 + koff + 8];
    __syncthreads();
    *(uint4*)&As[r][koff] = av0; *(uint4*)&As[r][koff + 8] = av1;
    *(uint4*)&Bs[r][koff] = bv0; *(uint4*)&Bs[r][koff + 8] = bv1;
    __syncthreads();
    bf16x8 af[4], bfr[4];
    #pragma unroll
    for (int mi = 0; mi < 4; ++mi)
      af[mi] = *(const bf16x8*)&As[wm + mi * 16 + l16][quad * 8];
    #pragma unroll
    for (int ni = 0; ni < 4; ++ni)
      bfr[ni] = *(const bf16x8*)&Bs[wn + ni * 16 + l16][quad * 8];
    #pragma unroll
    for (int mi = 0; mi < 4; ++mi)
      #pragma unroll
      for (int ni = 0; ni < 4; ++ni)
        acc[mi][ni] = __builtin_amdgcn_mfma_f32_16x16x32_bf16(
            af[mi], bfr[ni], acc[mi][ni], 0, 0, 0);
  }
  #pragma unroll
  for (int ni = 0; ni < 4; ++ni) {
    const int col = col0 + wn + ni * 16 + l16;
    const float bv = bias[col];
    #pragma unroll
    for (int mi = 0; mi < 4; ++mi) {
      #pragma unroll
      for (int rg = 0; rg < 4; ++rg) {
        const int row = row0 + wm + mi * 16 + quad * 4 + rg;
        C[(long)row * 2048 + col] = acc[mi][ni][rg] + bv;
      }
    }
  }
}

// fast transcendentals: v_exp_f32 + v_rcp_f32 (~1e-6 err << tol)
__device__ __forceinline__ float fast_sigmoid(float x) {
  return __builtin_amdgcn_rcpf(1.f + __expf(-x));
}
__device__ __forceinline__ float fast_tanh(float x) {
  const float xc = fmaxf(x, -30.f);
  const float e = __expf(-2.f * xc);
  return (1.f - e) * __builtin_amdgcn_rcpf(1.f + e);
}

__device__ __forceinline__ unsigned long long poll_ld(
    const unsigned long long* p) {
  return __hip_atomic_load(p, __ATOMIC_RELAXED, __HIP_MEMORY_SCOPE_AGENT);
}

// ============================================================
// K5 v11: v9 structure (tid-based poll — R10's permutation reverted:
// it cost 320cyc/step via scattered hl writes and saved nothing) plus:
//  (E) TWO-outstanding alternating poll: sampling period ~RT/2
//      instead of RT. Bounded issue (<=2 loads in flight per thread,
//      ~436 req/cyc chip-wide = 2x v9, 20x below v8's meltdown).
//      Max-detect over the 512 samplers drops ~300 cyc/step.
//  (F) publisher/writer split: kq<2 lanes both run the epilogue
//      (both load gates); kq==0 ONLY publishes the hbuf packet;
//      kq==1 does hidden_seq/h_t/c_t stores. Publisher's vmem queue
//      holds nothing but the 8B publish -> its next-step poll drain
//      waits one ack, not out-store acks.
// ============================================================
__global__ __launch_bounds__(512, 1) void k5_lstm(
    const float* __restrict__ gates, const float* __restrict__ whh,
    float* __restrict__ out, unsigned long long* hbuf) {
  const int s   = blockIdx.x & 15;       // unit-slice
  const int b   = blockIdx.x >> 4;       // batch = sync domain
  const int tid = threadIdx.x;           // 512 threads
  const int kq  = tid & 15;              // k-chunk
  const int cq  = tid >> 4;              // unit offset 0..31
  const int j0  = s * 32;
  const int unit = j0 + cq;
  const int slot = (tid >> 5) * 36 + (tid & 31);

  __shared__ __align__(16) float Wl[256 * 128];  // staging, 128 KB
  __shared__ __align__(16) float hl[2][576];     // parity; chunk*36+pos

  f2 wrA[32], wrB[32];
  for (int rnd = 0; rnd < 2; ++rnd) {
    for (int i = tid * 4; i < 256 * 128; i += 512 * 4) {
      const int k = i >> 7, c = i & 127;
      *(float4*)&Wl[i] =
          *(const float4*)&whh[(rnd * 256 + k) * G4H + (c >> 5) * HS + j0 + (c & 31)];
    }
    __syncthreads();
    if ((kq >> 3) == rnd) {
      const int kb = (kq & 7) * 32;
      #pragma unroll
      for (int kk = 0; kk < 32; ++kk) {
        const int base = (kb + kk) * 128 + cq;
        wrA[kk].x = *(volatile const float*)&Wl[base];
        wrA[kk].y = *(volatile const float*)&Wl[base + 32];
        wrB[kk].x = *(volatile const float*)&Wl[base + 64];
        wrB[kk].y = *(volatile const float*)&Wl[base + 96];
      }
    }
    __syncthreads();
  }

  float c_reg = 0.f;   // cell state (maintained on kq<2 lanes)

  // gates pipeline (kq<2 lanes): g_cur = row t, g_n1 = row t+1
  float4 g_cur = {0, 0, 0, 0}, g_n1 = {0, 0, 0, 0};
  const float* gbase = gates + (long)b * TT * G4H + unit;
  if (kq < 2) {
    g_cur.x = gbase[0];            g_cur.y = gbase[HS];
    g_cur.z = gbase[2 * HS];       g_cur.w = gbase[3 * HS];
    const float* g1 = gbase + G4H;
    g_n1.x = g1[0];                g_n1.y = g1[HS];
    g_n1.z = g1[2 * HS];           g_n1.w = g1[3 * HS];
  }

  for (int t = 0; t < TT; ++t) {
    const int par = t & 1;
    if (t > 0) {
      // two-outstanding alternating poll of my unit's packet (tag>=t)
      const unsigned long long* ha =
          hbuf + (((t - 1) & 1) * BB + b) * HS + tid;
      unsigned long long p0 = poll_ld(ha);
      unsigned long long p1 = poll_ld(ha);
      while ((unsigned)(p0 >> 32) < (unsigned)t) {
        p0 = p1;
        p1 = poll_ld(ha);
      }
      hl[par][slot] = __uint_as_float((unsigned)p0);
    }
    // issue gates row t+2 (>=1 full step old at the next vmcnt drain)
    float4 g_n2 = {0, 0, 0, 0};
    if (kq < 2) {
      const int tn = (t + 2 < TT) ? t + 2 : TT - 1;
      const float* g2 = gbase + (long)tn * G4H;
      g_n2.x = g2[0];        g_n2.y = g2[HS];
      g_n2.z = g2[2 * HS];   g_n2.w = g2[3 * HS];
    }
    // raw barrier: order LDS only; do NOT drain vmcnt
    __asm__ __volatile__("s_waitcnt lgkmcnt(0)\ns_barrier" ::: "memory");
    f2 acc01 = {0.f, 0.f}, acc23 = {0.f, 0.f};
    if (t > 0) {
      const float* hb = &hl[par][kq * 36];
      #pragma unroll
      for (int i = 0; i < 8; ++i) {
        const float4 h4 = *(const float4*)(hb + i * 4);
        const f2 hx = {h4.x, h4.x}, hy = {h4.y, h4.y};
        const f2 hz = {h4.z, h4.z}, hw = {h4.w, h4.w};
        acc01 += wrA[i * 4 + 0] * hx;  acc23 += wrB[i * 4 + 0] * hx;
        acc01 += wrA[i * 4 + 1] * hy;  acc23 += wrB[i * 4 + 1] * hy;
        acc01 += wrA[i * 4 + 2] * hz;  acc23 += wrB[i * 4 + 2] * hz;
        acc01 += wrA[i * 4 + 3] * hw;  acc23 += wrB[i * 4 + 3] * hw;
      }
    }
    #pragma unroll
    for (int off = 1; off <= 8; off <<= 1) {
      acc01.x += __shfl_xor(acc01.x, off);
      acc01.y += __shfl_xor(acc01.y, off);
      acc23.x += __shfl_xor(acc23.x, off);
      acc23.y += __shfl_xor(acc23.y, off);
    }
    // epilogue on kq<2 (butterfly left the sums in ALL 16 kq lanes):
    // kq==0 publishes only; kq==1 does the out stores.
    if (kq < 2) {
      const float I = fast_sigmoid(acc01.x + g_cur.x);
      const float F = fast_sigmoid(acc01.y + g_cur.y);
      const float G = fast_tanh(acc23.x + g_cur.z);
      const float O = fast_sigmoid(acc23.y + g_cur.w);
      c_reg = F * c_reg + I * G;
      const float h = O * fast_tanh(c_reg);
      if (kq == 0) {
        const unsigned long long pkt =
            ((unsigned long long)(unsigned)(t + 1) << 32) |
            (unsigned long long)__float_as_uint(h);
        __hip_atomic_store(&hbuf[(par * BB + b) * HS + unit], pkt,
                           __ATOMIC_RELAXED, __HIP_MEMORY_SCOPE_AGENT);
      } else {
        out[((long)b * TT + t) * HS + unit] = h;   // hidden_seq
        if (t == TT - 1) {
          out[(long)BB * TT * HS + b * HS + unit] = h;               // h_t
          out[(long)BB * TT * HS + BB * HS + b * HS + unit] = c_reg; // c_t
        }
      }
    }
    g_cur = g_n1;
    g_n1 = g_n2;
  }
}

// ============================================================
extern "C" void kernel_launch(void* const* d_in, const int* in_sizes, int n_in,
                              void* d_out, int out_size, void* d_ws,
                              size_t ws_size, hipStream_t stream) {
  const float* x    = (const float*)d_in[0];
  const float* w1   = (const float*)d_in[1];
  const float* b1   = (const float*)d_in[2];
  const float* w2   = (const float*)d_in[3];
  const float* b2   = (const float*)d_in[4];
  const float* wih  = (const float*)d_in[5];
  const float* whh  = (const float*)d_in[6];
  const float* bias = (const float*)d_in[7];
  float* out = (float*)d_out;

  float* ws = (float*)d_ws;
  float* s_buf  = ws;                       // dead after k2
  float* e_buf  = ws + 65536;
  float* i_buf  = ws + 131072;
  ushort_t* Mb  = (ushort_t*)(ws + 196608);   // bf16 M
  ushort_t* Wtb = (ushort_t*)(ws + 1245184);  // bf16 W_ih^T
  float* g_buf  = ws + 2293760;
  unsigned long long* hbuf64 = (unsigned long long*)ws;  // overlays s

  k0w_transpose<<<128, 256, 0, stream>>>(wih, Wtb);
  k1_score<<<512, 256, 0, stream>>>(x, w1, b1, w2, b2, s_buf);
  k2_prefix<<<BB * RR, 512, 0, stream>>>(s_buf, e_buf, i_buf);
  k3_mix<<<64, 64, 0, stream>>>(x, e_buf, i_buf, Mb);
  k4_mfma<<<64 * 16, 256, 0, stream>>>(Mb, Wtb, bias, g_buf);
  // zero packet tags (ws re-poisoned 0xAA each call); after k2's s reads
  hipMemsetAsync(hbuf64, 0, 2 * BB * HS * sizeof(unsigned long long), stream);
  k5_lstm<<<256, 512, 0, stream>>>(g_buf, whh, out, hbuf64);
}